// Round 5
// baseline (216.296 us; speedup 1.0000x reference)
//
#include <hip/hip_runtime.h>
#include <hip/hip_bf16.h>

typedef __bf16 bf16x8 __attribute__((ext_vector_type(8)));
typedef float f32x4 __attribute__((ext_vector_type(4)));
typedef unsigned int u32;
typedef unsigned short u16;
typedef u32 u32x4 __attribute__((ext_vector_type(4)));
typedef u16 u16x4 __attribute__((ext_vector_type(4)));
typedef u16 u16x8 __attribute__((ext_vector_type(8)));

// manual RNE f32->bf16 (prep kernels only; hot path uses compiler casts)
__device__ __forceinline__ u16 f2bf(float x) {
  u32 u = __float_as_uint(x);
  return (u16)((u + 0x7FFFu + ((u >> 16) & 1u)) >> 16);
}

// compiler cast -> v_cvt_pk_bf16_f32 (RNE) on gfx950
__device__ __forceinline__ u16 cvt_bf16(float x) {
  __bf16 h = (__bf16)x;
  return __builtin_bit_cast(u16, h);
}

__device__ __forceinline__ bf16x8 ld_frag_lds(const u16* base, int byteOff) {
  u32x4 v = *(const u32x4*)((const char*)base + byteOff);
  return __builtin_bit_cast(bf16x8, v);
}

__device__ __forceinline__ bf16x8 ld_frag_glb(const u16* p) {
  u32x4 v = *(const u32x4*)p;
  return __builtin_bit_cast(bf16x8, v);
}

// ---------------------------------------------------------------------------
// prep_w: bf16 MFMA A-operand fragments.
// wfA (64 KB): Wcat = [W2a rows 64:128 ; W2a rows 192:256]  (K=128, N=256)
//   wfA[((ntg*4+ks)*64+lane)*8+q] = Wcat[ks*32+(lane>>4)*8+q][ntg*16+(lane&15)]
// wfB (32 KB): W2b (K=256, N=64), 8 ksteps, 4 ntiles.
// ---------------------------------------------------------------------------
__global__ void prep_w_kernel(const float* __restrict__ W2a, const float* __restrict__ W2b,
                              u16* __restrict__ wfA, u16* __restrict__ wfB) {
  int t = blockIdx.x * 256 + threadIdx.x;
  if (t < 4096) {  // wfA: 16 ntg * 4 ks * 64 lanes
    int lane = t & 63;
    int ks = (t >> 6) & 3;
    int ntg = t >> 8;
    int col = (ntg << 4) + (lane & 15);
    int k = (ks << 5) + ((lane >> 4) << 3);           // 0..120, multiple of 8
    int row = (k < 64) ? (64 + k) : (128 + k);        // Wa1 rows 64:128, Wa3 rows 192:256
#pragma unroll
    for (int q = 0; q < 8; ++q)
      wfA[t * 8 + q] = f2bf(W2a[(row + q) * 256 + col]);
  } else if (t < 6144) {  // wfB: 4 ntg * 8 ks * 64 lanes
    int t2 = t - 4096;
    int lane = t2 & 63;
    int ks = (t2 >> 6) & 7;
    int ntg = t2 >> 9;
    int col = (ntg << 4) + (lane & 15);
    int k = (ks << 5) + ((lane >> 4) << 3);
#pragma unroll
    for (int q = 0; q < 8; ++q)
      wfB[t2 * 8 + q] = f2bf(W2b[(k + q) * 64 + col]);
  }
}

// ---------------------------------------------------------------------------
// prep_T: T0[b,n,:] = e1[b,n]@W2a[0:64]   + b2a   (f32, 2 MB)
//         T2[b,n,:] = e1[b,n]@W2a[128:192]        (f32, 2 MB)
// One block per (b,n); thread t computes column t of both.
// ---------------------------------------------------------------------------
__global__ __launch_bounds__(256) void prep_T_kernel(
    const float* __restrict__ emb1, const float* __restrict__ W2a,
    const float* __restrict__ b2a, float* __restrict__ T0, float* __restrict__ T2) {
  __shared__ float e1row[64];
  int bn = blockIdx.x;
  int t = threadIdx.x;
  if (t < 64) e1row[t] = emb1[bn * 64 + t];
  __syncthreads();
  float a0 = b2a[t];
  float a2 = 0.f;
#pragma unroll 8
  for (int k = 0; k < 64; ++k) {
    float e = e1row[k];
    a0 += e * W2a[k * 256 + t];
    a2 += e * W2a[(128 + k) * 256 + t];
  }
  T0[(size_t)bn * 256 + t] = a0;
  T2[(size_t)bn * 256 + t] = a2;
}

// ---------------------------------------------------------------------------
// Fused kernel. Blocks [0,8192): out2. Blocks [8192,10240): out1 (tail fill).
//
// out2 block = (b, i, j-tile of 64):
//   X row r = [emb2[b,j0+r,i,:] | emb2[b,i,j0+r,:]]  (128 bf16, 256B rows)
//   GEMM1 (K=128, swapped operands): P^T = Wcat^T @ X^T
//   epilogue: H = relu(P + T0[b,j] + T2[b,i])  -> H LDS (bf16, [64][256])
//   GEMM2 (K=256): O^T = W2b^T @ H^T;  out += b2b
// LDS: X 16 KB + H 32 KB = 48 KB -> 3 blocks/CU. Two barriers only
// (stage->bar->GEMM1->Hwrite->bar->GEMM2): X and H are separate buffers.
// XOR swizzle byte ^= (row&7)<<4 on both buffers.
// __launch_bounds__(256,2): proven no-spill (R2/R3: any tighter bound spills).
// ---------------------------------------------------------------------------
__global__ __launch_bounds__(256, 2) void fused_kernel(
    const float* __restrict__ emb1, const float* __restrict__ emb2,
    const float* __restrict__ W1a, const float* __restrict__ b1a,
    const float* __restrict__ W1b, const float* __restrict__ b1b,
    const float* __restrict__ b2b,
    const u16* __restrict__ wfA, const u16* __restrict__ wfB,
    const float* __restrict__ T0, const float* __restrict__ T2,
    float* __restrict__ out1, float* __restrict__ out2) {
  __shared__ __align__(16) u16 SH[24576];  // 48 KB: X = [0,8192) u16, H = [8192,24576)

  int blk = blockIdx.x;
  int t = threadIdx.x;

  if (blk >= 8192) {
    // ---------------- out1 path ----------------
    int bi = blk - 8192;
    float* f = (float*)SH;
    float* smax = f;
    float* smin = f + 256;
    float* cat1 = f + 512;
    float* h    = f + 704;

    int d = t & 63, q = t >> 6;
    const float* base = emb2 + (size_t)bi * 256 * 64;
    float vmax = -INFINITY, vmin = INFINITY;
    for (int j = q; j < 256; j += 4) {
      float v = base[j * 64 + d];
      vmax = fmaxf(vmax, v);
      vmin = fminf(vmin, v);
    }
    smax[q * 64 + d] = vmax;
    smin[q * 64 + d] = vmin;
    __syncthreads();
    if (t < 64) {
      float mx = fmaxf(fmaxf(smax[t], smax[64 + t]), fmaxf(smax[128 + t], smax[192 + t]));
      float mn = fminf(fminf(smin[t], smin[64 + t]), fminf(smin[128 + t], smin[192 + t]));
      cat1[t] = emb1[bi * 64 + t];
      cat1[64 + t] = mx;
      cat1[128 + t] = mn;
    }
    __syncthreads();
    if (t < 128) {
      float acc = b1a[t];
      for (int k = 0; k < 192; ++k) acc += cat1[k] * W1a[k * 128 + t];
      h[t] = fmaxf(acc, 0.f);
    }
    __syncthreads();
    if (t < 64) {
      float acc = b1b[t];
      for (int k = 0; k < 128; ++k) acc += h[k] * W1b[k * 64 + t];
      out1[bi * 64 + t] = acc;
    }
    return;
  }

  // ---------------- out2 path ----------------
  int b = blk >> 10;
  int i = (blk >> 2) & 255;
  int j0 = (blk & 3) << 6;
  int lane = t & 63;
  int w = t >> 6;
  int lr = lane & 15;
  int lg = lane >> 4;

  const u16* X = SH;          // 16 KB, rows 256B
  const u16* H = SH + 8192;   // 32 KB, rows 512B
  char* Xb = (char*)SH;
  char* Hb = (char*)SH + 16384;

  // ---- stage X: 64 rows x 128 bf16. thread: r=t>>2, q=t&3 -> 32 floats ----
  {
    int r = t >> 2;
    int q = t & 3;
    const float* s1 = emb2 + (((size_t)b * 256 + (j0 + r)) * 256 + i) * 64;
    const float* s3 = emb2 + (((size_t)b * 256 + i) * 256 + (j0 + r)) * 64;
    const float* src = (q < 2) ? (s1 + (q << 5)) : (s3 + ((q - 2) << 5));
    float4 v[8];
#pragma unroll
    for (int u = 0; u < 8; ++u) v[u] = *(const float4*)(src + (u << 2));
#pragma unroll
    for (int u = 0; u < 4; ++u) {
      float4 a0 = v[u * 2], a1 = v[u * 2 + 1];
      u16x8 o = {cvt_bf16(a0.x), cvt_bf16(a0.y), cvt_bf16(a0.z), cvt_bf16(a0.w),
                 cvt_bf16(a1.x), cvt_bf16(a1.y), cvt_bf16(a1.z), cvt_bf16(a1.w)};
      int off = (r * 256 + (q << 6) + (u << 4)) ^ ((r & 7) << 4);
      *(u16x8*)(Xb + off) = o;
    }
  }
  __syncthreads();

  // ---- GEMM1: K=128, wave w owns n in [w*64, w*64+64) ----
  f32x4 acc1[4][4];
#pragma unroll
  for (int m = 0; m < 4; ++m)
#pragma unroll
    for (int nt = 0; nt < 4; ++nt) acc1[m][nt] = (f32x4){0.f, 0.f, 0.f, 0.f};

#pragma unroll
  for (int ks = 0; ks < 4; ++ks) {
    int kByte = (ks << 6) + (lg << 4);
    bf16x8 a[4];
#pragma unroll
    for (int m = 0; m < 4; ++m) {
      int off = (((m << 4) + lr) * 256 + kByte) ^ ((lr & 7) << 4);
      a[m] = ld_frag_lds(X, off);
    }
    bf16x8 bw[4];
#pragma unroll
    for (int nt = 0; nt < 4; ++nt)
      bw[nt] = ld_frag_glb(wfA + (size_t)((((w << 2) + nt) * 4 + ks) * 64 + lane) * 8);
#pragma unroll
    for (int m = 0; m < 4; ++m)
#pragma unroll
      for (int nt = 0; nt < 4; ++nt)
        acc1[m][nt] = __builtin_amdgcn_mfma_f32_16x16x32_bf16(bw[nt], a[m], acc1[m][nt], 0, 0, 0);
  }

  // ---- epilogue: H = relu(P + T0[b,j] + T2[b,i]) -> H LDS (no barrier needed) ----
  // acc1[m][nt][e]: j = m*16+lr, n = (w*4+nt)*16 + lg*4 + e
#pragma unroll
  for (int nt = 0; nt < 4; ++nt) {
    int n_lo = (((w << 2) + nt) << 4) + (lg << 2);
    float4 t2v = *(const float4*)(T2 + ((size_t)b * 256 + i) * 256 + n_lo);
#pragma unroll
    for (int m = 0; m < 4; ++m) {
      int jrow = (m << 4) + lr;
      float4 t0v = *(const float4*)(T0 + ((size_t)b * 256 + j0 + jrow) * 256 + n_lo);
      u16x4 o = {cvt_bf16(fmaxf(acc1[m][nt][0] + t0v.x + t2v.x, 0.f)),
                 cvt_bf16(fmaxf(acc1[m][nt][1] + t0v.y + t2v.y, 0.f)),
                 cvt_bf16(fmaxf(acc1[m][nt][2] + t0v.z + t2v.z, 0.f)),
                 cvt_bf16(fmaxf(acc1[m][nt][3] + t0v.w + t2v.w, 0.f))};
      int off = (jrow * 512 + n_lo * 2) ^ ((lr & 7) << 4);
      *(u16x4*)(Hb + off) = o;
    }
  }
  __syncthreads();

  // ---- GEMM2: K=256, wave w owns d in [w*16, w*16+16) ----
  f32x4 acc2[4];
#pragma unroll
  for (int jt = 0; jt < 4; ++jt) acc2[jt] = (f32x4){0.f, 0.f, 0.f, 0.f};

#pragma unroll
  for (int ks = 0; ks < 8; ++ks) {
    int kByte = (ks << 6) + (lg << 4);
    bf16x8 bwB = ld_frag_glb(wfB + (size_t)(((w << 3) + ks) * 64 + lane) * 8);
#pragma unroll
    for (int jt = 0; jt < 4; ++jt) {
      int off = (((jt << 4) + lr) * 512 + kByte) ^ ((lr & 7) << 4);
      bf16x8 h = ld_frag_lds(H, off);
      acc2[jt] = __builtin_amdgcn_mfma_f32_16x16x32_bf16(bwB, h, acc2[jt], 0, 0, 0);
    }
  }

  // ---- store: acc2[jt][e]: j = jt*16+lr, d = w*16 + lg*4 + e ----
  float4 bias2 = *(const float4*)(b2b + (w << 4) + (lg << 2));
  float* obase = out2 + (((size_t)b * 256 + i) * 256 + j0) * 64 + (w << 4) + (lg << 2);
#pragma unroll
  for (int jt = 0; jt < 4; ++jt) {
    float4 v = {acc2[jt][0] + bias2.x, acc2[jt][1] + bias2.y,
                acc2[jt][2] + bias2.z, acc2[jt][3] + bias2.w};
    *(float4*)(obase + (size_t)((jt << 4) + lr) * 64) = v;
  }
}

extern "C" void kernel_launch(void* const* d_in, const int* in_sizes, int n_in,
                              void* d_out, int out_size, void* d_ws, size_t ws_size,
                              hipStream_t stream) {
  const float* emb1 = (const float*)d_in[0];
  const float* emb2 = (const float*)d_in[1];
  const float* W1a  = (const float*)d_in[2];
  const float* b1a  = (const float*)d_in[3];
  const float* W1b  = (const float*)d_in[4];
  const float* b1b  = (const float*)d_in[5];
  const float* W2a  = (const float*)d_in[6];
  const float* b2a  = (const float*)d_in[7];
  const float* W2b  = (const float*)d_in[8];
  const float* b2b  = (const float*)d_in[9];

  float* out = (float*)d_out;
  u16* wfA = (u16*)d_ws;                       // 32768 u16 = 64 KB
  u16* wfB = wfA + 32768;                      // 16384 u16 = 32 KB
  float* T0 = (float*)(wfB + 16384);           // 8*256*256 f32 = 2 MB
  float* T2 = T0 + 8 * 256 * 256;              // 2 MB

  prep_w_kernel<<<24, 256, 0, stream>>>(W2a, W2b, wfA, wfB);
  prep_T_kernel<<<2048, 256, 0, stream>>>(emb1, W2a, b2a, T0, T2);
  fused_kernel<<<10240, 256, 0, stream>>>(emb1, emb2, W1a, b1a, W1b, b1b,
                                          b2b, wfA, wfB, T0, T2,
                                          out, out + 8 * 256 * 64);
}